// Round 8
// baseline (164.616 us; speedup 1.0000x reference)
//
#include <hip/hip_runtime.h>

// Fused grouped-QKV GEMM: out[t,kv,g,d] = sum_e in[t,e]*W[e,kv,g,d] + bias
// M=64, K=4096, N=6144. fp32 in/out. W read (100.7MB fp32) dominates ->
// floor ~16us @6.3TB/s.
//
// R8: barrier-free per-wave pipeline. Each wave GLDS-stages its OWN LDS
// region (W 4KB fp32 + A 4KB bf16 per buffer, x2 buffers) and reads back
// only its own writes -> no __syncthreads in the K-loop; sync is a manual
// s_waitcnt vmcnt(8) (exactly 8 GLDS per tile, nothing else in the vmcnt
// stream). 2 blocks/CU x 4 waves x 8KB in flight ~= 64KB/CU outstanding.
// Cross-wave k-reduce via one LDS pass at block end; fp16 partials (6.3MB)
// + tiny reduce kernel. No atomics.

#define N_COLS 6144
#define K_DIM  4096
#define Q_SZ   (64 * 4096)
#define K_OFF  Q_SZ
#define V_OFF  (Q_SZ + 64 * 1024)
#define OUT_ELEMS 393216   // 64*6144
#define IN_ELEMS  262144   // 64*4096
#define NT     192         // n-tiles of 32
#define KSPLIT 8           // 512 k per block -> 1536 blocks = 3 rounds @2/CU
#define TILES  4           // per wave: 128 k in 4 tiles of BK=32

typedef __bf16 bf16x8 __attribute__((ext_vector_type(8)));
typedef float  f32x4  __attribute__((ext_vector_type(4)));
typedef unsigned int u32x4 __attribute__((ext_vector_type(4)));
typedef unsigned short us8 __attribute__((ext_vector_type(8)));

__device__ unsigned short g_abuf[IN_ELEMS];  // bf16 input, rewritten each call

__device__ __forceinline__ unsigned short f2bf_rne(float f) {
    unsigned int u = __float_as_uint(f);
    u += 0x7FFFu + ((u >> 16) & 1u);
    return (unsigned short)(u >> 16);
}

__device__ __forceinline__ unsigned int pack_pair(float lo, float hi) {
    unsigned int a = __float_as_uint(lo), b = __float_as_uint(hi);
    a += 0x7FFFu + ((a >> 16) & 1u);
    b += 0x8000u & ~0x7FFFu;  // placeholder to keep SSA simple
    b = __float_as_uint(hi);
    b += 0x7FFFu + ((b >> 16) & 1u);
    return (b & 0xFFFF0000u) | (a >> 16);
}

__device__ __forceinline__ int out_index(int t, int n) {
    const int kv = n / 768;
    const int g  = (n >> 7) % 6;
    const int d  = n & 127;
    if (g < 4)  return t * 4096 + kv * 512 + g * 128 + d;   // q
    if (g == 4) return K_OFF + t * 1024 + kv * 128 + d;     // k
    return V_OFF + t * 1024 + kv * 128 + d;                 // v
}

__global__ __launch_bounds__(256)
void init_kernel(const float* __restrict__ in) {
    const int i = blockIdx.x * 256 + threadIdx.x;
    if (i < IN_ELEMS) g_abuf[i] = f2bf_rne(in[i]);
}

// async global->LDS, 16B per lane (wave-uniform LDS base + lane*16)
#define GLDS(gp, lp) __builtin_amdgcn_global_load_lds(                        \
    (const __attribute__((address_space(1))) void*)(gp),                      \
    (__attribute__((address_space(3))) void*)(lp), 16, 0, 0)

__global__ __launch_bounds__(256, 2)
void qkv_gemm(const float* __restrict__ w, _Float16* __restrict__ part) {
    // 4 waves x 2 buffers x 8KB (W fp32 4KB + A bf16 4KB), wave-private
    __shared__ __align__(16) char lds_raw[65536];

    const int tid  = threadIdx.x;
    const int nt   = blockIdx.x % NT;    // adjacent blocks: adjacent n, same k
    const int kq   = blockIdx.x / NT;
    const int n0   = nt * 32;
    const int wid  = tid >> 6;
    const int lane = tid & 63;
    const int l15  = lane & 15;
    const int kblk = lane >> 4;

    f32x4 acc[2][4];
    #pragma unroll
    for (int a = 0; a < 2; ++a)
        #pragma unroll
        for (int b = 0; b < 4; ++b) acc[a][b] = (f32x4){0.f, 0.f, 0.f, 0.f};

    const int kwave = kq * 512 + wid * 128;   // this wave's 128-k slice

    // ---- issue one tile's 8 GLDS (4 W + 4 A) into buffer `buf` ----
    #define ISSUE_TILE(buf, s) do {                                           \
        const int kc_ = kwave + (s) * 32;                                     \
        char* wb_ = lds_raw + (wid * 2 + (buf)) * 8192;                       \
        const float* wg_ = w + (size_t)kc_ * N_COLS + n0;                     \
        GLDS(wg_ + (size_t)((0 * 64 + lane) >> 3) * N_COLS + ((0 * 64 + lane) & 7) * 4, wb_ + (0 * 64 + lane) * 16); \
        GLDS(wg_ + (size_t)((1 * 64 + lane) >> 3) * N_COLS + ((1 * 64 + lane) & 7) * 4, wb_ + (1 * 64 + lane) * 16); \
        GLDS(wg_ + (size_t)((2 * 64 + lane) >> 3) * N_COLS + ((2 * 64 + lane) & 7) * 4, wb_ + (2 * 64 + lane) * 16); \
        GLDS(wg_ + (size_t)((3 * 64 + lane) >> 3) * N_COLS + ((3 * 64 + lane) & 7) * 4, wb_ + (3 * 64 + lane) * 16); \
        const unsigned short* ag_ = g_abuf + kc_;                             \
        GLDS(ag_ + (size_t)((0 * 64 + lane) >> 2) * K_DIM + ((0 * 64 + lane) & 3) * 8, wb_ + 4096 + (0 * 64 + lane) * 16); \
        GLDS(ag_ + (size_t)((1 * 64 + lane) >> 2) * K_DIM + ((1 * 64 + lane) & 3) * 8, wb_ + 4096 + (1 * 64 + lane) * 16); \
        GLDS(ag_ + (size_t)((2 * 64 + lane) >> 2) * K_DIM + ((2 * 64 + lane) & 3) * 8, wb_ + 4096 + (2 * 64 + lane) * 16); \
        GLDS(ag_ + (size_t)((3 * 64 + lane) >> 2) * K_DIM + ((3 * 64 + lane) & 3) * 8, wb_ + 4096 + (3 * 64 + lane) * 16); \
    } while (0)

    ISSUE_TILE(0, 0);

    #pragma unroll
    for (int s = 0; s < TILES; ++s) {
        if (s + 1 < TILES) {
            ISSUE_TILE((s + 1) & 1, s + 1);
            asm volatile("s_waitcnt vmcnt(8)" ::: "memory");  // current staged
        } else {
            asm volatile("s_waitcnt vmcnt(0)" ::: "memory");
        }

        const char* wb = lds_raw + (wid * 2 + (s & 1)) * 8192;
        const float* Wf = (const float*)wb;                      // [32k][32n]
        const unsigned short* Ab = (const unsigned short*)(wb + 4096); // [64t][32k]

        // A-frags: m = mi*16+l15, k = kblk*8..+7  (one b128 each)
        us8 af[4];
        #pragma unroll
        for (int mi = 0; mi < 4; ++mi)
            af[mi] = *(const us8*)(Ab + (mi * 16 + l15) * 32 + kblk * 8);

        // B-frags: n = nf*16+l15, k = kblk*8+j; pack fp32->bf16 pairs
        #pragma unroll
        for (int nf = 0; nf < 2; ++nf) {
            const int nn = nf * 16 + l15;
            u32x4 bu;
            #pragma unroll
            for (int j2 = 0; j2 < 4; ++j2)
                bu[j2] = pack_pair(Wf[(kblk * 8 + 2 * j2) * 32 + nn],
                                   Wf[(kblk * 8 + 2 * j2 + 1) * 32 + nn]);
            const bf16x8 bv = __builtin_bit_cast(bf16x8, bu);
            #pragma unroll
            for (int mi = 0; mi < 4; ++mi)
                acc[nf][mi] = __builtin_amdgcn_mfma_f32_16x16x32_bf16(
                    __builtin_bit_cast(bf16x8, af[mi]), bv, acc[nf][mi], 0, 0, 0);
        }
    }

    // ---- cross-wave k-reduce in LDS (one barrier total) ----
    // wave wid's region (its own 16KB) as fp16 [lane][32]; j=(nf*4+mi)*4+r
    _Float16* red = (_Float16*)(lds_raw + wid * 16384);
    #pragma unroll
    for (int nf = 0; nf < 2; ++nf)
        #pragma unroll
        for (int mi = 0; mi < 4; ++mi)
            #pragma unroll
            for (int r = 0; r < 4; ++r)
                red[lane * 32 + (nf * 4 + mi) * 4 + r] =
                    (_Float16)acc[nf][mi][r];
    __syncthreads();

    // thread t: token row = t>>2, cols (t&3)*8..+7 of the 32-wide n tile
    const int row = tid >> 2;          // = mi*16 + kblk*4 + r
    const int q   = tid & 3;
    const int mi_ = row >> 4, kb_ = (row >> 2) & 3, r_ = row & 3;
    #pragma unroll
    for (int c = 0; c < 8; ++c) {
        const int nl   = q * 8 + c;
        const int lsrc = kb_ * 16 + (nl & 15);
        const int j    = ((nl >> 4) * 4 + mi_) * 4 + r_;
        float s = 0.f;
        #pragma unroll
        for (int wv = 0; wv < 4; ++wv)
            s += (float)((const _Float16*)(lds_raw + wv * 16384))[lsrc * 32 + j];
        part[(size_t)kq * OUT_ELEMS + row * N_COLS + n0 + nl] = (_Float16)s;
    }
}

// sum KSPLIT fp16 partials + bias, scatter to q|k|v
__global__ __launch_bounds__(256)
void qkv_reduce(const _Float16* __restrict__ part, const float* __restrict__ bias,
                float* __restrict__ out) {
    const int i = blockIdx.x * 256 + threadIdx.x;   // 0..393215
    const int t = i / N_COLS;
    const int n = i % N_COLS;
    float s = bias[n];
    #pragma unroll
    for (int kq = 0; kq < KSPLIT; ++kq)
        s += (float)part[(size_t)kq * OUT_ELEMS + i];
    out[out_index(t, n)] = s;
}

extern "C" void kernel_launch(void* const* d_in, const int* in_sizes, int n_in,
                              void* d_out, int out_size, void* d_ws, size_t ws_size,
                              hipStream_t stream) {
    const float* in   = (const float*)d_in[0];  // [64, 4096]
    const float* w    = (const float*)d_in[1];  // [4096, 8, 6, 128]
    const float* bias = (const float*)d_in[2];  // [8, 6, 128]
    float* out = (float*)d_out;
    _Float16* part = (_Float16*)d_ws;           // 8 * 786KB = 6.3MB fp16

    init_kernel<<<IN_ELEMS / 256, 256, 0, stream>>>(in);
    qkv_gemm<<<NT * KSPLIT, 256, 0, stream>>>(w, part);
    qkv_reduce<<<OUT_ELEMS / 256, 256, 0, stream>>>(part, bias, out);
}